// Round 15
// baseline (700.260 us; speedup 1.0000x reference)
//
#include <hip/hip_runtime.h>

// ---------------------------------------------------------------------------
// GIN forward on MI355X. CSR-by-dst built once per call; scatter pre-gathers
// edge_attr into CSR order (8-float rows: 7 attrs + src id). Aggregation:
// STATIC wave->8-node map, flat edge loop in 8-wide groups, IN-ORDER issue+
// consume (pipelined/work-stealing variants all regressed: FETCH 36->150MB).
// MLP: WAVE-DECOUPLED — each wave owns a private 32-row LDS slab (row-major,
// stride 68), does stage -> GEMM1 -> in-place relu rewrite -> GEMM2 -> store
// with NO block barriers (wave-internal LDS ordering suffices); barriers only
// bracket the final BN-stat reduction. Weights stream from global (L1
// broadcast). BN affine derived from raw per-layer stat slots by consumers.
// int32 inputs. hbuf = layer output, tbuf = agg intermediate.
// ---------------------------------------------------------------------------

__global__ void hist_k(const int* __restrict__ dst, int* __restrict__ cnt, int E) {
  int stride = gridDim.x * blockDim.x;
  for (int i = blockIdx.x * blockDim.x + threadIdx.x; i < E; i += stride)
    atomicAdd(&cnt[dst[i]], 1);
}

__global__ void scan_a_k(const int* __restrict__ deg, int* __restrict__ rowptr,
                         int* __restrict__ bsum, int n) {
  __shared__ int s[256];
  int i = blockIdx.x * 256 + threadIdx.x;
  int v = (i < n) ? deg[i] : 0;
  s[threadIdx.x] = v;
  __syncthreads();
  for (int off = 1; off < 256; off <<= 1) {
    int t = (threadIdx.x >= off) ? s[threadIdx.x - off] : 0;
    __syncthreads();
    s[threadIdx.x] += t;
    __syncthreads();
  }
  if (i < n) rowptr[i] = s[threadIdx.x] - v;   // exclusive within block
  if (threadIdx.x == 255) bsum[blockIdx.x] = s[255];
}

__global__ void scan_b_k(int* __restrict__ bsum, int nb) {
  __shared__ int s[512];
  int t = threadIdx.x;
  int v = (t < nb) ? bsum[t] : 0;
  s[t] = v;
  __syncthreads();
  for (int off = 1; off < 512; off <<= 1) {
    int u = (t >= off) ? s[t - off] : 0;
    __syncthreads();
    s[t] += u;
    __syncthreads();
  }
  if (t < nb) bsum[t] = s[t] - v;              // exclusive block offsets
}

__global__ void scan_c_k(int* __restrict__ rowptr, int* __restrict__ cur,
                         const int* __restrict__ bsum, int n, int E) {
  int i = blockIdx.x * 256 + threadIdx.x;
  if (i < n) {
    int r = rowptr[i] + bsum[blockIdx.x];
    rowptr[i] = r;
    cur[i] = r;                                 // scatter cursor copy
  }
  if (i == 0) rowptr[n] = E;
}

// Scatter edges into CSR order, pre-gathering edge_attr. Each CSR slot is
// 8 floats: [0..6] = edge_attr row, [7] = src node id (as int bits).
__global__ void scatter_k(const int* __restrict__ src, const int* __restrict__ dst,
                          int* __restrict__ cur, float* __restrict__ sea,
                          const float* __restrict__ ea, int E) {
  int stride = gridDim.x * blockDim.x;
  for (int i = blockIdx.x * blockDim.x + threadIdx.x; i < E; i += stride) {
    int d = dst[i];
    int pos = atomicAdd(&cur[d], 1);
    const float* a = ea + (size_t)i * 7;
    float4 lo = make_float4(a[0], a[1], a[2], a[3]);
    float4 hi = make_float4(a[4], a[5], a[6], __int_as_float(src[i]));
    float4* o = (float4*)(sea + (size_t)pos * 8);
    o[0] = lo;
    o[1] = hi;
  }
}

// Aggregation: static map, wave serves NPW consecutive nodes. Flat edge
// loop over the wave's whole CSR range in 8-wide groups, in-order issue and
// immediate consume (empirically optimal; deeper pipelines regress FETCH).
// MODE 0: layer 0, single-row node table. MODE 1: layer 0, general table.
// MODE 2: later layers, h = relu(affine(prev z)) gathered per edge.
#define NPW 8
template<int MODE>
__global__ __launch_bounds__(256)
void agg_k(const float* __restrict__ hprev, const int* __restrict__ x,
           const float* __restrict__ ntab, const int* __restrict__ rowptr,
           const float* __restrict__ sea, const float* __restrict__ ewl,
           const float* __restrict__ ebl, const float* __restrict__ statsP,
           const float* __restrict__ gamP, const float* __restrict__ betP,
           float* __restrict__ zout, int n) {
  int wv = (blockIdx.x * blockDim.x + threadIdx.x) >> 6;
  int lane = threadIdx.x & 63;
  int g0 = wv * NPW;
  if (g0 >= n) return;
  int gend = g0 + NPW; if (gend > n) gend = n;

  float ew_[7];
#pragma unroll
  for (int k = 0; k < 7; k++) ew_[k] = ewl[k * 64 + lane];
  float ebv = ebl[lane];

  float cnst = 0.f, sc = 1.f, sh = 0.f;
  if (MODE == 0) cnst = ntab[lane];
  if (MODE == 2) {
    float s1 = statsP[lane], s2 = statsP[64 + lane];
    float mu = s1 / (float)n;
    float var = s2 / (float)n - mu * mu;
    sc = gamP[lane] * rsqrtf(var + 1e-5f);
    sh = betP[lane] - mu * sc;
  }

  // raw self/gather load (affine+relu applied at use for MODE 2)
  auto raw_ld = [&](int row) -> float {
    if (MODE == 0) return 0.f;
    if (MODE == 1) {
      int xv = __builtin_amdgcn_readfirstlane(x[row]);
      return ntab[(size_t)xv * 64 + lane];
    }
    return hprev[(size_t)row * 64 + lane];
  };
  auto finish_h = [&](float v) -> float {
    if (MODE == 0) return cnst;
    if (MODE == 1) return v;
    return fmaxf(fmaf(v, sc, sh), 0.f);
  };

  int P1 = __builtin_amdgcn_readfirstlane(rowptr[gend]);
  int p0 = __builtin_amdgcn_readfirstlane(rowptr[g0]);
  int nd = g0;
  int pn = __builtin_amdgcn_readfirstlane(rowptr[nd + 1]);
  float selfv = raw_ld(nd);
  float acc = 0.f;

  for (int p = p0; p < P1; p += 8) {
    // scalar attr rows + src ids for 8 edges (clamped); SGPR-resident
    const float* R[8];
    int s[8];
#pragma unroll
    for (int u = 0; u < 8; u++) {
      int t = p + u;
      int q = t < P1 ? t : P1 - 1;
      R[u] = sea + (size_t)q * 8;
      s[u] = __builtin_amdgcn_readfirstlane(__float_as_int(R[u][7]));
    }
    // 8 independent per-lane gathers in flight
    float h[8];
#pragma unroll
    for (int u = 0; u < 8; u++) h[u] = (MODE == 0) ? cnst : raw_ld(s[u]);
    // edge embeddings (overlaps gather latency; SGPR x VGPR fma)
    float m[8];
#pragma unroll
    for (int u = 0; u < 8; u++) m[u] = ebv;
#pragma unroll
    for (int k = 0; k < 7; k++) {
#pragma unroll
      for (int u = 0; u < 8; u++) m[u] = fmaf(R[u][k], ew_[k], m[u]);
    }
    // consume with node-boundary flush
#pragma unroll
    for (int u = 0; u < 8; u++) {
      if (p + u < P1) {
        while (p + u >= pn) {
          zout[(size_t)nd * 64 + lane] = finish_h(selfv) + acc;
          nd++;
          selfv = raw_ld(nd);
          pn = __builtin_amdgcn_readfirstlane(rowptr[nd + 1]);
          acc = 0.f;
        }
        acc += fmaxf(finish_h(h[u]) + m[u], 0.f);
      }
    }
  }
  // drain: flush current node and trailing zero-edge nodes
  while (nd < gend) {
    zout[(size_t)nd * 64 + lane] = finish_h(selfv) + acc;
    nd++;
    acc = 0.f;
    if (nd < gend) selfv = raw_ld(nd);
  }
}

// MLP: z2 = relu(z @ w1 + b1) @ w2 + b2, per-dim sum/sumsq into this
// layer's stat slot. WAVE-DECOUPLED: each wave owns a 32-row slab
// (row-major, stride 68 floats = 272B 16B-aligned). No block barriers in
// the hot path — wave-internal LDS ordering (lgkmcnt) is sufficient since
// each wave touches only its own slab. Thread tile 8 rows x 4 cols.
#define MSTR 68
__global__ __launch_bounds__(256, 4)
void mlp_k(const float* __restrict__ zin, const float* __restrict__ w1l,
           const float* __restrict__ b1l, const float* __restrict__ w2l,
           const float* __restrict__ b2l, float* __restrict__ zout,
           float* __restrict__ statslot, int n) {
  __shared__ float slab[4][32 * MSTR];
  __shared__ float red[128];
  int tid = threadIdx.x;
  int wv = tid >> 6, lane = tid & 63;
  int tx = lane & 15, tyl = lane >> 4;
  if (tid < 128) red[tid] = 0.f;
  __syncthreads();                       // red ready before any wave's atomics

  int r0 = blockIdx.x * 128 + wv * 32;   // this wave's 32 rows
  float* S = slab[wv];

  // stage 32 rows row-major (coalesced b128 in, b128 LDS writes)
  {
    const float4* gz = (const float4*)(zin + (size_t)r0 * 64);
#pragma unroll
    for (int it = 0; it < 8; it++) {
      int f4 = it * 64 + lane;           // 0..511 = 32 rows x 16 quads
      int row = f4 >> 4, kq = f4 & 15;
      float4 v = make_float4(0.f, 0.f, 0.f, 0.f);
      if (r0 + row < n) v = gz[f4];
      *(float4*)&S[row * MSTR + kq * 4] = v;
    }
  }

  // GEMM1: t = z @ w1 + b1 (weights from global, L1 broadcast)
  const float4 b1v = *(const float4*)(b1l + tx * 4);
  float t[8][4];
#pragma unroll
  for (int rr = 0; rr < 8; rr++) {
    t[rr][0] = b1v.x; t[rr][1] = b1v.y; t[rr][2] = b1v.z; t[rr][3] = b1v.w;
  }
#pragma unroll 8
  for (int k = 0; k < 64; k++) {
    float a[8];
#pragma unroll
    for (int rr = 0; rr < 8; rr++) a[rr] = S[(tyl * 8 + rr) * MSTR + k];
    float4 b = *(const float4*)(w1l + k * 64 + tx * 4);
#pragma unroll
    for (int rr = 0; rr < 8; rr++) {
      t[rr][0] = fmaf(a[rr], b.x, t[rr][0]);
      t[rr][1] = fmaf(a[rr], b.y, t[rr][1]);
      t[rr][2] = fmaf(a[rr], b.z, t[rr][2]);
      t[rr][3] = fmaf(a[rr], b.w, t[rr][3]);
    }
  }

  // relu(t) written back in-place, row-major (wave-internal order is safe)
#pragma unroll
  for (int rr = 0; rr < 8; rr++) {
    float4 w;
    w.x = fmaxf(t[rr][0], 0.f); w.y = fmaxf(t[rr][1], 0.f);
    w.z = fmaxf(t[rr][2], 0.f); w.w = fmaxf(t[rr][3], 0.f);
    *(float4*)&S[(tyl * 8 + rr) * MSTR + tx * 4] = w;
  }

  // GEMM2: o = relu(t) @ w2 + b2
  const float4 b2v = *(const float4*)(b2l + tx * 4);
  float o[8][4];
#pragma unroll
  for (int rr = 0; rr < 8; rr++) {
    o[rr][0] = b2v.x; o[rr][1] = b2v.y; o[rr][2] = b2v.z; o[rr][3] = b2v.w;
  }
#pragma unroll 8
  for (int k = 0; k < 64; k++) {
    float a[8];
#pragma unroll
    for (int rr = 0; rr < 8; rr++) a[rr] = S[(tyl * 8 + rr) * MSTR + k];
    float4 b = *(const float4*)(w2l + k * 64 + tx * 4);
#pragma unroll
    for (int rr = 0; rr < 8; rr++) {
      o[rr][0] = fmaf(a[rr], b.x, o[rr][0]);
      o[rr][1] = fmaf(a[rr], b.y, o[rr][1]);
      o[rr][2] = fmaf(a[rr], b.z, o[rr][2]);
      o[rr][3] = fmaf(a[rr], b.w, o[rr][3]);
    }
  }

  // store + BN stat partials (valid rows only)
  float s1[4] = {0.f, 0.f, 0.f, 0.f}, s2[4] = {0.f, 0.f, 0.f, 0.f};
#pragma unroll
  for (int rr = 0; rr < 8; rr++) {
    int grow = r0 + tyl * 8 + rr;
    if (grow < n) {
      float4 v = make_float4(o[rr][0], o[rr][1], o[rr][2], o[rr][3]);
      *(float4*)(zout + (size_t)grow * 64 + tx * 4) = v;
#pragma unroll
      for (int cc = 0; cc < 4; cc++) {
        s1[cc] += o[rr][cc];
        s2[cc] = fmaf(o[rr][cc], o[rr][cc], s2[cc]);
      }
    }
  }
#pragma unroll
  for (int cc = 0; cc < 4; cc++) {             // reduce over the 4 tyl groups
    s1[cc] += __shfl_xor(s1[cc], 16); s1[cc] += __shfl_xor(s1[cc], 32);
    s2[cc] += __shfl_xor(s2[cc], 16); s2[cc] += __shfl_xor(s2[cc], 32);
  }
  if (tyl == 0) {                              // lanes 0..15 of each wave
#pragma unroll
    for (int cc = 0; cc < 4; cc++) {
      atomicAdd(&red[tx * 4 + cc], s1[cc]);
      atomicAdd(&red[64 + tx * 4 + cc], s2[cc]);
    }
  }
  __syncthreads();
  if (tid < 128) atomicAdd(&statslot[tid], red[tid]);
}

// Segment-mean pool with last-layer BN affine fused (no relu on last layer).
__global__ void pool_k(const float* __restrict__ z2, const float* __restrict__ stats,
                       const float* __restrict__ gam, const float* __restrict__ bet,
                       const int* __restrict__ batch, float* __restrict__ gsum,
                       float* __restrict__ gcnt, int n, int ch) {
  int wid = (blockIdx.x * blockDim.x + threadIdx.x) >> 6;
  int lane = threadIdx.x & 63;
  int v0 = wid * ch;
  if (v0 >= n) return;
  int v1 = v0 + ch; if (v1 > n) v1 = n;
  float st1 = stats[lane], st2 = stats[64 + lane];
  float mu = st1 / (float)n;
  float var = st2 / (float)n - mu * mu;
  float sc = gam[lane] * rsqrtf(var + 1e-5f);
  float sh = bet[lane] - mu * sc;
  int curb = batch[v0];
  float acc = 0.f;
  int cnt = 0;
  for (int v = v0; v < v1; v++) {
    int b = batch[v];
    if (b != curb) {
      atomicAdd(&gsum[curb * 64 + lane], acc);
      if (lane == 0) atomicAdd(&gcnt[curb], (float)cnt);
      acc = 0.f; cnt = 0; curb = b;
    }
    acc += fmaf(z2[(size_t)v * 64 + lane], sc, sh);
    cnt++;
  }
  atomicAdd(&gsum[curb * 64 + lane], acc);
  if (lane == 0) atomicAdd(&gcnt[curb], (float)cnt);
}

__global__ void head_k(const float* __restrict__ gsum, const float* __restrict__ gcnt,
                       const float* __restrict__ pw, const float* __restrict__ pb,
                       float* __restrict__ out, int B, int C) {
  for (int idx = threadIdx.x; idx < B * C; idx += blockDim.x) {
    int g = idx / C, c = idx % C;
    float inv = 1.f / fmaxf(gcnt[g], 1.f);
    float s = pb[c];
    for (int d = 0; d < 64; d++)
      s = fmaf(gsum[g * 64 + d] * inv, pw[d * C + c], s);
    out[idx] = s;
  }
}

extern "C" void kernel_launch(void* const* d_in, const int* in_sizes, int n_in,
                              void* d_out, int out_size, void* d_ws, size_t ws_size,
                              hipStream_t stream) {
  const int*   x     = (const int*)d_in[0];
  const int*   ei    = (const int*)d_in[1];
  const float* ea    = (const float*)d_in[2];
  const int*   batch = (const int*)d_in[3];
  const float* ntab  = (const float*)d_in[4];
  const float* ew    = (const float*)d_in[5];
  const float* eb    = (const float*)d_in[6];
  const float* w1    = (const float*)d_in[7];
  const float* b1    = (const float*)d_in[8];
  const float* w2    = (const float*)d_in[9];
  const float* b2    = (const float*)d_in[10];
  const float* gamma = (const float*)d_in[11];
  const float* beta  = (const float*)d_in[12];
  const float* pw    = (const float*)d_in[13];
  const float* pb    = (const float*)d_in[14];
  float* out = (float*)d_out;

  int N = in_sizes[0];
  int E = in_sizes[1] / 2;
  int L = in_sizes[6] / 64;        // eb is (L, 64)
  int C = in_sizes[14];
  int B = out_size / C;
  bool tab1 = (in_sizes[4] == 64); // node_table has a single row

  const int* src = ei;
  const int* dst = ei + E;

  // workspace carve (256B aligned)
  char* ws = (char*)d_ws;
  auto alloc = [&](size_t bytes) -> char* {
    char* p = ws;
    ws += (bytes + 255) & ~(size_t)255;
    return p;
  };
  float* hbuf    = (float*)alloc((size_t)N * 64 * 4);  // layer output (MLP out)
  float* tbuf    = (float*)alloc((size_t)N * 64 * 4);  // agg intermediate
  int*   rowptr  = (int*)alloc((size_t)(N + 1) * 4);
  int*   cur     = (int*)alloc((size_t)N * 4);
  float* sea     = (float*)alloc((size_t)(E + 16) * 8 * 4); // CSR rows + pad
  int*   bsum    = (int*)alloc(512 * 4);
  float* bnstats = (float*)alloc((size_t)L * 128 * 4);     // per-layer stat slots
  float* gsum    = (float*)alloc((size_t)B * 64 * 4);
  float* gcnt    = (float*)alloc((size_t)B * 4);

  hipMemsetAsync(cur, 0, (size_t)N * 4, stream);
  hipMemsetAsync(bnstats, 0, (size_t)L * 128 * 4, stream);
  hipMemsetAsync(gsum, 0, (size_t)B * 64 * 4, stream);
  hipMemsetAsync(gcnt, 0, (size_t)B * 4, stream);

  // CSR build (reused across all layers)
  hist_k<<<2048, 256, 0, stream>>>(dst, cur, E);
  int NB = (N + 255) / 256;
  scan_a_k<<<NB, 256, 0, stream>>>(cur, rowptr, bsum, N);
  scan_b_k<<<1, 512, 0, stream>>>(bsum, NB);
  scan_c_k<<<NB, 256, 0, stream>>>(rowptr, cur, bsum, N, E);
  scatter_k<<<4096, 256, 0, stream>>>(src, dst, cur, sea, ea, E);

  int aggWaves = (N + NPW - 1) / NPW;
  int aggBlocks = (aggWaves * 64 + 255) / 256;
  int mlpBlocks = (N + 127) / 128;
  for (int l = 0; l < L; l++) {
    const float* ewl = ew + (size_t)l * 448;
    const float* ebl = eb + (size_t)l * 64;
    const float* stP = bnstats + (size_t)(l > 0 ? l - 1 : 0) * 128;
    const float* gmP = gamma + (size_t)(l > 0 ? l - 1 : 0) * 64;
    const float* btP = beta + (size_t)(l > 0 ? l - 1 : 0) * 64;
    // agg: reads hbuf (layers>0), writes tbuf
    if (l == 0) {
      if (tab1)
        agg_k<0><<<aggBlocks, 256, 0, stream>>>(hbuf, x, ntab, rowptr, sea, ewl,
                                                ebl, stP, gmP, btP, tbuf, N);
      else
        agg_k<1><<<aggBlocks, 256, 0, stream>>>(hbuf, x, ntab, rowptr, sea, ewl,
                                                ebl, stP, gmP, btP, tbuf, N);
    } else {
      agg_k<2><<<aggBlocks, 256, 0, stream>>>(hbuf, x, ntab, rowptr, sea, ewl,
                                              ebl, stP, gmP, btP, tbuf, N);
    }
    // MLP: reads tbuf, writes hbuf (the next layer's h / pool input)
    mlp_k<<<mlpBlocks, 256, 0, stream>>>(tbuf, w1 + (size_t)l * 4096,
                                         b1 + (size_t)l * 64,
                                         w2 + (size_t)l * 4096,
                                         b2 + (size_t)l * 64,
                                         hbuf, bnstats + (size_t)l * 128, N);
  }

  int ch = 64;
  int poolWaves = (N + ch - 1) / ch;
  int poolBlocks = (poolWaves + 3) / 4;
  pool_k<<<poolBlocks, 256, 0, stream>>>(hbuf,
                                         bnstats + (size_t)(L - 1) * 128,
                                         gamma + (size_t)(L - 1) * 64,
                                         beta + (size_t)(L - 1) * 64,
                                         batch, gsum, gcnt, N, ch);
  head_k<<<1, 256, 0, stream>>>(gsum, gcnt, pw, pb, out, B, C);
}

// Round 16
// 694.687 us; speedup vs baseline: 1.0080x; 1.0080x over previous
//
#include <hip/hip_runtime.h>

// ---------------------------------------------------------------------------
// GIN forward on MI355X. CSR-by-dst built once per call; scatter pre-gathers
// edge_attr into CSR order (8-float rows: 7 attrs + src id). Aggregation:
// STATIC wave->8-node map, flat edge loop in 8-wide groups, IN-ORDER issue+
// consume (pipelined/work-stealing variants all regressed: FETCH 36->150MB).
// MLP: 64x64 tiled GEMM (4x4 register tile, pad-68 transposed A, Ws staged
// in LDS, w2 prefetched to registers) -> 34.3KB LDS -> 4 blocks/CU, 2-way
// (free) LDS banking. BN affine derived from raw per-layer stat slots by
// consumers. int32 inputs. hbuf = layer output, tbuf = agg intermediate.
// ---------------------------------------------------------------------------

__global__ void hist_k(const int* __restrict__ dst, int* __restrict__ cnt, int E) {
  int stride = gridDim.x * blockDim.x;
  for (int i = blockIdx.x * blockDim.x + threadIdx.x; i < E; i += stride)
    atomicAdd(&cnt[dst[i]], 1);
}

__global__ void scan_a_k(const int* __restrict__ deg, int* __restrict__ rowptr,
                         int* __restrict__ bsum, int n) {
  __shared__ int s[256];
  int i = blockIdx.x * 256 + threadIdx.x;
  int v = (i < n) ? deg[i] : 0;
  s[threadIdx.x] = v;
  __syncthreads();
  for (int off = 1; off < 256; off <<= 1) {
    int t = (threadIdx.x >= off) ? s[threadIdx.x - off] : 0;
    __syncthreads();
    s[threadIdx.x] += t;
    __syncthreads();
  }
  if (i < n) rowptr[i] = s[threadIdx.x] - v;   // exclusive within block
  if (threadIdx.x == 255) bsum[blockIdx.x] = s[255];
}

__global__ void scan_b_k(int* __restrict__ bsum, int nb) {
  __shared__ int s[512];
  int t = threadIdx.x;
  int v = (t < nb) ? bsum[t] : 0;
  s[t] = v;
  __syncthreads();
  for (int off = 1; off < 512; off <<= 1) {
    int u = (t >= off) ? s[t - off] : 0;
    __syncthreads();
    s[t] += u;
    __syncthreads();
  }
  if (t < nb) bsum[t] = s[t] - v;              // exclusive block offsets
}

__global__ void scan_c_k(int* __restrict__ rowptr, int* __restrict__ cur,
                         const int* __restrict__ bsum, int n, int E) {
  int i = blockIdx.x * 256 + threadIdx.x;
  if (i < n) {
    int r = rowptr[i] + bsum[blockIdx.x];
    rowptr[i] = r;
    cur[i] = r;                                 // scatter cursor copy
  }
  if (i == 0) rowptr[n] = E;
}

// Scatter edges into CSR order, pre-gathering edge_attr. Each CSR slot is
// 8 floats: [0..6] = edge_attr row, [7] = src node id (as int bits).
__global__ void scatter_k(const int* __restrict__ src, const int* __restrict__ dst,
                          int* __restrict__ cur, float* __restrict__ sea,
                          const float* __restrict__ ea, int E) {
  int stride = gridDim.x * blockDim.x;
  for (int i = blockIdx.x * blockDim.x + threadIdx.x; i < E; i += stride) {
    int d = dst[i];
    int pos = atomicAdd(&cur[d], 1);
    const float* a = ea + (size_t)i * 7;
    float4 lo = make_float4(a[0], a[1], a[2], a[3]);
    float4 hi = make_float4(a[4], a[5], a[6], __int_as_float(src[i]));
    float4* o = (float4*)(sea + (size_t)pos * 8);
    o[0] = lo;
    o[1] = hi;
  }
}

// Aggregation: static map, wave serves NPW consecutive nodes. Flat edge
// loop over the wave's whole CSR range in 8-wide groups, in-order issue and
// immediate consume (empirically optimal; deeper pipelines regress FETCH).
// MODE 0: layer 0, single-row node table. MODE 1: layer 0, general table.
// MODE 2: later layers, h = relu(affine(prev z)) gathered per edge.
#define NPW 8
template<int MODE>
__global__ __launch_bounds__(256)
void agg_k(const float* __restrict__ hprev, const int* __restrict__ x,
           const float* __restrict__ ntab, const int* __restrict__ rowptr,
           const float* __restrict__ sea, const float* __restrict__ ewl,
           const float* __restrict__ ebl, const float* __restrict__ statsP,
           const float* __restrict__ gamP, const float* __restrict__ betP,
           float* __restrict__ zout, int n) {
  int wv = (blockIdx.x * blockDim.x + threadIdx.x) >> 6;
  int lane = threadIdx.x & 63;
  int g0 = wv * NPW;
  if (g0 >= n) return;
  int gend = g0 + NPW; if (gend > n) gend = n;

  float ew_[7];
#pragma unroll
  for (int k = 0; k < 7; k++) ew_[k] = ewl[k * 64 + lane];
  float ebv = ebl[lane];

  float cnst = 0.f, sc = 1.f, sh = 0.f;
  if (MODE == 0) cnst = ntab[lane];
  if (MODE == 2) {
    float s1 = statsP[lane], s2 = statsP[64 + lane];
    float mu = s1 / (float)n;
    float var = s2 / (float)n - mu * mu;
    sc = gamP[lane] * rsqrtf(var + 1e-5f);
    sh = betP[lane] - mu * sc;
  }

  // raw self/gather load (affine+relu applied at use for MODE 2)
  auto raw_ld = [&](int row) -> float {
    if (MODE == 0) return 0.f;
    if (MODE == 1) {
      int xv = __builtin_amdgcn_readfirstlane(x[row]);
      return ntab[(size_t)xv * 64 + lane];
    }
    return hprev[(size_t)row * 64 + lane];
  };
  auto finish_h = [&](float v) -> float {
    if (MODE == 0) return cnst;
    if (MODE == 1) return v;
    return fmaxf(fmaf(v, sc, sh), 0.f);
  };

  int P1 = __builtin_amdgcn_readfirstlane(rowptr[gend]);
  int p0 = __builtin_amdgcn_readfirstlane(rowptr[g0]);
  int nd = g0;
  int pn = __builtin_amdgcn_readfirstlane(rowptr[nd + 1]);
  float selfv = raw_ld(nd);
  float acc = 0.f;

  for (int p = p0; p < P1; p += 8) {
    // scalar attr rows + src ids for 8 edges (clamped); SGPR-resident
    const float* R[8];
    int s[8];
#pragma unroll
    for (int u = 0; u < 8; u++) {
      int t = p + u;
      int q = t < P1 ? t : P1 - 1;
      R[u] = sea + (size_t)q * 8;
      s[u] = __builtin_amdgcn_readfirstlane(__float_as_int(R[u][7]));
    }
    // 8 independent per-lane gathers in flight
    float h[8];
#pragma unroll
    for (int u = 0; u < 8; u++) h[u] = (MODE == 0) ? cnst : raw_ld(s[u]);
    // edge embeddings (overlaps gather latency; SGPR x VGPR fma)
    float m[8];
#pragma unroll
    for (int u = 0; u < 8; u++) m[u] = ebv;
#pragma unroll
    for (int k = 0; k < 7; k++) {
#pragma unroll
      for (int u = 0; u < 8; u++) m[u] = fmaf(R[u][k], ew_[k], m[u]);
    }
    // consume with node-boundary flush
#pragma unroll
    for (int u = 0; u < 8; u++) {
      if (p + u < P1) {
        while (p + u >= pn) {
          zout[(size_t)nd * 64 + lane] = finish_h(selfv) + acc;
          nd++;
          selfv = raw_ld(nd);
          pn = __builtin_amdgcn_readfirstlane(rowptr[nd + 1]);
          acc = 0.f;
        }
        acc += fmaxf(finish_h(h[u]) + m[u], 0.f);
      }
    }
  }
  // drain: flush current node and trailing zero-edge nodes
  while (nd < gend) {
    zout[(size_t)nd * 64 + lane] = finish_h(selfv) + acc;
    nd++;
    acc = 0.f;
    if (nd < gend) selfv = raw_ld(nd);
  }
}

// MLP: z2 = relu(z @ w1 + b1) @ w2 + b2, per-dim sum/sumsq into this
// layer's stat slot. Tiled GEMM: 256 threads (16x16), 64 rows x 64 cols,
// 4x4 register tile (rows ty*4..+3, cols tx*4..+3). A transposed in LDS
// with stride 68 (one b128 feed, 2-way=free banking). w1/w2 staged in Ws
// (w2 prefetched to registers at start). 34.3KB LDS -> 4 blocks/CU.
#define ASTR 68
__global__ __launch_bounds__(256, 4)
void mlp_k(const float* __restrict__ zin, const float* __restrict__ w1l,
           const float* __restrict__ b1l, const float* __restrict__ w2l,
           const float* __restrict__ b2l, float* __restrict__ zout,
           float* __restrict__ statslot, int n) {
  __shared__ float As[64 * ASTR];
  __shared__ float Ws[4096];
  __shared__ float red[128];
  int tid = threadIdx.x;
  int tx = tid & 15, ty = tid >> 4;
  if (tid < 128) red[tid] = 0.f;
  int r0 = blockIdx.x * 64;

  // prefetch w2 into registers (retires during A-staging + GEMM1)
  float4 w2r[4];
  {
    const float4* wb = (const float4*)w2l;
#pragma unroll
    for (int it = 0; it < 4; it++) w2r[it] = wb[it * 256 + tid];
  }

  // stage A transposed + w1
  {
    const float4* gz = (const float4*)(zin + (size_t)r0 * 64);
#pragma unroll
    for (int it = 0; it < 4; it++) {
      int f4 = it * 256 + tid;                 // 0..1023 = 64 rows x 16 quads
      int row = f4 >> 4, kq = f4 & 15;
      float4 v = make_float4(0.f, 0.f, 0.f, 0.f);
      if (r0 + row < n) v = gz[f4];
      As[(4 * kq + 0) * ASTR + row] = v.x;
      As[(4 * kq + 1) * ASTR + row] = v.y;
      As[(4 * kq + 2) * ASTR + row] = v.z;
      As[(4 * kq + 3) * ASTR + row] = v.w;
    }
    const float4* wa = (const float4*)w1l;
    float4* wd = (float4*)Ws;
#pragma unroll
    for (int it = 0; it < 4; it++) wd[it * 256 + tid] = wa[it * 256 + tid];
  }
  __syncthreads();

  const float4 b1v = *(const float4*)(b1l + tx * 4);
  float t[4][4];
#pragma unroll
  for (int rr = 0; rr < 4; rr++) {
    t[rr][0] = b1v.x; t[rr][1] = b1v.y; t[rr][2] = b1v.z; t[rr][3] = b1v.w;
  }
#pragma unroll 8
  for (int k = 0; k < 64; k++) {
    float4 aA = *(const float4*)&As[k * ASTR + ty * 4];
    float4 b = *(const float4*)&Ws[k * 64 + tx * 4];
    float a[4] = {aA.x, aA.y, aA.z, aA.w};
#pragma unroll
    for (int rr = 0; rr < 4; rr++) {
      t[rr][0] = fmaf(a[rr], b.x, t[rr][0]);
      t[rr][1] = fmaf(a[rr], b.y, t[rr][1]);
      t[rr][2] = fmaf(a[rr], b.z, t[rr][2]);
      t[rr][3] = fmaf(a[rr], b.w, t[rr][3]);
    }
  }
  __syncthreads();                             // As, Ws fully consumed

  // relu(t) transposed into As; w2 regs -> Ws (no global latency here)
#pragma unroll
  for (int cc = 0; cc < 4; cc++)
#pragma unroll
    for (int rr = 0; rr < 4; rr++)
      As[(tx * 4 + cc) * ASTR + ty * 4 + rr] = fmaxf(t[rr][cc], 0.f);
  {
    float4* wd = (float4*)Ws;
#pragma unroll
    for (int it = 0; it < 4; it++) wd[it * 256 + tid] = w2r[it];
  }
  __syncthreads();

  const float4 b2v = *(const float4*)(b2l + tx * 4);
  float o[4][4];
#pragma unroll
  for (int rr = 0; rr < 4; rr++) {
    o[rr][0] = b2v.x; o[rr][1] = b2v.y; o[rr][2] = b2v.z; o[rr][3] = b2v.w;
  }
#pragma unroll 8
  for (int k = 0; k < 64; k++) {
    float4 aA = *(const float4*)&As[k * ASTR + ty * 4];
    float4 b = *(const float4*)&Ws[k * 64 + tx * 4];
    float a[4] = {aA.x, aA.y, aA.z, aA.w};
#pragma unroll
    for (int rr = 0; rr < 4; rr++) {
      o[rr][0] = fmaf(a[rr], b.x, o[rr][0]);
      o[rr][1] = fmaf(a[rr], b.y, o[rr][1]);
      o[rr][2] = fmaf(a[rr], b.z, o[rr][2]);
      o[rr][3] = fmaf(a[rr], b.w, o[rr][3]);
    }
  }

  // store + BN stat partials (valid rows only)
  float s1[4] = {0.f, 0.f, 0.f, 0.f}, s2[4] = {0.f, 0.f, 0.f, 0.f};
#pragma unroll
  for (int rr = 0; rr < 4; rr++) {
    int grow = r0 + ty * 4 + rr;
    if (grow < n) {
      float4 v = make_float4(o[rr][0], o[rr][1], o[rr][2], o[rr][3]);
      *(float4*)(zout + (size_t)grow * 64 + tx * 4) = v;
#pragma unroll
      for (int cc = 0; cc < 4; cc++) {
        s1[cc] += o[rr][cc];
        s2[cc] = fmaf(o[rr][cc], o[rr][cc], s2[cc]);
      }
    }
  }
#pragma unroll
  for (int cc = 0; cc < 4; cc++) {             // reduce over the 4 ty-groups in wave
    s1[cc] += __shfl_xor(s1[cc], 16); s1[cc] += __shfl_xor(s1[cc], 32);
    s2[cc] += __shfl_xor(s2[cc], 16); s2[cc] += __shfl_xor(s2[cc], 32);
  }
  if ((tid & 48) == 0) {                       // one ty-group per wave
#pragma unroll
    for (int cc = 0; cc < 4; cc++) {
      atomicAdd(&red[tx * 4 + cc], s1[cc]);
      atomicAdd(&red[64 + tx * 4 + cc], s2[cc]);
    }
  }
  __syncthreads();
  if (tid < 128) atomicAdd(&statslot[tid], red[tid]);
}

// Segment-mean pool with last-layer BN affine fused (no relu on last layer).
__global__ void pool_k(const float* __restrict__ z2, const float* __restrict__ stats,
                       const float* __restrict__ gam, const float* __restrict__ bet,
                       const int* __restrict__ batch, float* __restrict__ gsum,
                       float* __restrict__ gcnt, int n, int ch) {
  int wid = (blockIdx.x * blockDim.x + threadIdx.x) >> 6;
  int lane = threadIdx.x & 63;
  int v0 = wid * ch;
  if (v0 >= n) return;
  int v1 = v0 + ch; if (v1 > n) v1 = n;
  float st1 = stats[lane], st2 = stats[64 + lane];
  float mu = st1 / (float)n;
  float var = st2 / (float)n - mu * mu;
  float sc = gam[lane] * rsqrtf(var + 1e-5f);
  float sh = bet[lane] - mu * sc;
  int curb = batch[v0];
  float acc = 0.f;
  int cnt = 0;
  for (int v = v0; v < v1; v++) {
    int b = batch[v];
    if (b != curb) {
      atomicAdd(&gsum[curb * 64 + lane], acc);
      if (lane == 0) atomicAdd(&gcnt[curb], (float)cnt);
      acc = 0.f; cnt = 0; curb = b;
    }
    acc += fmaf(z2[(size_t)v * 64 + lane], sc, sh);
    cnt++;
  }
  atomicAdd(&gsum[curb * 64 + lane], acc);
  if (lane == 0) atomicAdd(&gcnt[curb], (float)cnt);
}

__global__ void head_k(const float* __restrict__ gsum, const float* __restrict__ gcnt,
                       const float* __restrict__ pw, const float* __restrict__ pb,
                       float* __restrict__ out, int B, int C) {
  for (int idx = threadIdx.x; idx < B * C; idx += blockDim.x) {
    int g = idx / C, c = idx % C;
    float inv = 1.f / fmaxf(gcnt[g], 1.f);
    float s = pb[c];
    for (int d = 0; d < 64; d++)
      s = fmaf(gsum[g * 64 + d] * inv, pw[d * C + c], s);
    out[idx] = s;
  }
}

extern "C" void kernel_launch(void* const* d_in, const int* in_sizes, int n_in,
                              void* d_out, int out_size, void* d_ws, size_t ws_size,
                              hipStream_t stream) {
  const int*   x     = (const int*)d_in[0];
  const int*   ei    = (const int*)d_in[1];
  const float* ea    = (const float*)d_in[2];
  const int*   batch = (const int*)d_in[3];
  const float* ntab  = (const float*)d_in[4];
  const float* ew    = (const float*)d_in[5];
  const float* eb    = (const float*)d_in[6];
  const float* w1    = (const float*)d_in[7];
  const float* b1    = (const float*)d_in[8];
  const float* w2    = (const float*)d_in[9];
  const float* b2    = (const float*)d_in[10];
  const float* gamma = (const float*)d_in[11];
  const float* beta  = (const float*)d_in[12];
  const float* pw    = (const float*)d_in[13];
  const float* pb    = (const float*)d_in[14];
  float* out = (float*)d_out;

  int N = in_sizes[0];
  int E = in_sizes[1] / 2;
  int L = in_sizes[6] / 64;        // eb is (L, 64)
  int C = in_sizes[14];
  int B = out_size / C;
  bool tab1 = (in_sizes[4] == 64); // node_table has a single row

  const int* src = ei;
  const int* dst = ei + E;

  // workspace carve (256B aligned)
  char* ws = (char*)d_ws;
  auto alloc = [&](size_t bytes) -> char* {
    char* p = ws;
    ws += (bytes + 255) & ~(size_t)255;
    return p;
  };
  float* hbuf    = (float*)alloc((size_t)N * 64 * 4);  // layer output (MLP out)
  float* tbuf    = (float*)alloc((size_t)N * 64 * 4);  // agg intermediate
  int*   rowptr  = (int*)alloc((size_t)(N + 1) * 4);
  int*   cur     = (int*)alloc((size_t)N * 4);
  float* sea     = (float*)alloc((size_t)(E + 16) * 8 * 4); // CSR rows + pad
  int*   bsum    = (int*)alloc(512 * 4);
  float* bnstats = (float*)alloc((size_t)L * 128 * 4);     // per-layer stat slots
  float* gsum    = (float*)alloc((size_t)B * 64 * 4);
  float* gcnt    = (float*)alloc((size_t)B * 4);

  hipMemsetAsync(cur, 0, (size_t)N * 4, stream);
  hipMemsetAsync(bnstats, 0, (size_t)L * 128 * 4, stream);
  hipMemsetAsync(gsum, 0, (size_t)B * 64 * 4, stream);
  hipMemsetAsync(gcnt, 0, (size_t)B * 4, stream);

  // CSR build (reused across all layers)
  hist_k<<<2048, 256, 0, stream>>>(dst, cur, E);
  int NB = (N + 255) / 256;
  scan_a_k<<<NB, 256, 0, stream>>>(cur, rowptr, bsum, N);
  scan_b_k<<<1, 512, 0, stream>>>(bsum, NB);
  scan_c_k<<<NB, 256, 0, stream>>>(rowptr, cur, bsum, N, E);
  scatter_k<<<4096, 256, 0, stream>>>(src, dst, cur, sea, ea, E);

  int aggWaves = (N + NPW - 1) / NPW;
  int aggBlocks = (aggWaves * 64 + 255) / 256;
  int mlpBlocks = (N + 63) / 64;
  for (int l = 0; l < L; l++) {
    const float* ewl = ew + (size_t)l * 448;
    const float* ebl = eb + (size_t)l * 64;
    const float* stP = bnstats + (size_t)(l > 0 ? l - 1 : 0) * 128;
    const float* gmP = gamma + (size_t)(l > 0 ? l - 1 : 0) * 64;
    const float* btP = beta + (size_t)(l > 0 ? l - 1 : 0) * 64;
    // agg: reads hbuf (layers>0), writes tbuf
    if (l == 0) {
      if (tab1)
        agg_k<0><<<aggBlocks, 256, 0, stream>>>(hbuf, x, ntab, rowptr, sea, ewl,
                                                ebl, stP, gmP, btP, tbuf, N);
      else
        agg_k<1><<<aggBlocks, 256, 0, stream>>>(hbuf, x, ntab, rowptr, sea, ewl,
                                                ebl, stP, gmP, btP, tbuf, N);
    } else {
      agg_k<2><<<aggBlocks, 256, 0, stream>>>(hbuf, x, ntab, rowptr, sea, ewl,
                                              ebl, stP, gmP, btP, tbuf, N);
    }
    // MLP: reads tbuf, writes hbuf (the next layer's h / pool input)
    mlp_k<<<mlpBlocks, 256, 0, stream>>>(tbuf, w1 + (size_t)l * 4096,
                                         b1 + (size_t)l * 64,
                                         w2 + (size_t)l * 4096,
                                         b2 + (size_t)l * 64,
                                         hbuf, bnstats + (size_t)l * 128, N);
  }

  int ch = 64;
  int poolWaves = (N + ch - 1) / ch;
  int poolBlocks = (poolWaves + 3) / 4;
  pool_k<<<poolBlocks, 256, 0, stream>>>(hbuf,
                                         bnstats + (size_t)(L - 1) * 128,
                                         gamma + (size_t)(L - 1) * 64,
                                         beta + (size_t)(L - 1) * 64,
                                         batch, gsum, gcnt, N, ch);
  head_k<<<1, 256, 0, stream>>>(gsum, gcnt, pw, pb, out, B, C);
}

// Round 17
// 612.131 us; speedup vs baseline: 1.1440x; 1.1349x over previous
//
#include <hip/hip_runtime.h>

// ---------------------------------------------------------------------------
// GIN forward on MI355X — best-measured configuration (round 12, 637 us).
// CSR-by-dst built once per call; scatter pre-gathers edge_attr into CSR
// order (8-float rows: 7 attrs + src id). Aggregation: STATIC wave->8-node
// map, flat edge loop in 8-wide groups, IN-ORDER issue+consume (pipelined /
// work-stealing / vector-path variants all regressed: FETCH 36->150MB).
// MLP: 128x64 tiled GEMM (8x4 register tile, pad-132 transposed A in LDS,
// w1/w2 staged through a 16KB Ws buffer). BN affine derived from raw
// per-layer stat slots by consumers. int32 inputs.
// hbuf = layer output, tbuf = agg intermediate.
// ---------------------------------------------------------------------------

__global__ void hist_k(const int* __restrict__ dst, int* __restrict__ cnt, int E) {
  int stride = gridDim.x * blockDim.x;
  for (int i = blockIdx.x * blockDim.x + threadIdx.x; i < E; i += stride)
    atomicAdd(&cnt[dst[i]], 1);
}

__global__ void scan_a_k(const int* __restrict__ deg, int* __restrict__ rowptr,
                         int* __restrict__ bsum, int n) {
  __shared__ int s[256];
  int i = blockIdx.x * 256 + threadIdx.x;
  int v = (i < n) ? deg[i] : 0;
  s[threadIdx.x] = v;
  __syncthreads();
  for (int off = 1; off < 256; off <<= 1) {
    int t = (threadIdx.x >= off) ? s[threadIdx.x - off] : 0;
    __syncthreads();
    s[threadIdx.x] += t;
    __syncthreads();
  }
  if (i < n) rowptr[i] = s[threadIdx.x] - v;   // exclusive within block
  if (threadIdx.x == 255) bsum[blockIdx.x] = s[255];
}

__global__ void scan_b_k(int* __restrict__ bsum, int nb) {
  __shared__ int s[512];
  int t = threadIdx.x;
  int v = (t < nb) ? bsum[t] : 0;
  s[t] = v;
  __syncthreads();
  for (int off = 1; off < 512; off <<= 1) {
    int u = (t >= off) ? s[t - off] : 0;
    __syncthreads();
    s[t] += u;
    __syncthreads();
  }
  if (t < nb) bsum[t] = s[t] - v;              // exclusive block offsets
}

__global__ void scan_c_k(int* __restrict__ rowptr, int* __restrict__ cur,
                         const int* __restrict__ bsum, int n, int E) {
  int i = blockIdx.x * 256 + threadIdx.x;
  if (i < n) {
    int r = rowptr[i] + bsum[blockIdx.x];
    rowptr[i] = r;
    cur[i] = r;                                 // scatter cursor copy
  }
  if (i == 0) rowptr[n] = E;
}

// Scatter edges into CSR order, pre-gathering edge_attr. Each CSR slot is
// 8 floats: [0..6] = edge_attr row, [7] = src node id (as int bits).
__global__ void scatter_k(const int* __restrict__ src, const int* __restrict__ dst,
                          int* __restrict__ cur, float* __restrict__ sea,
                          const float* __restrict__ ea, int E) {
  int stride = gridDim.x * blockDim.x;
  for (int i = blockIdx.x * blockDim.x + threadIdx.x; i < E; i += stride) {
    int d = dst[i];
    int pos = atomicAdd(&cur[d], 1);
    const float* a = ea + (size_t)i * 7;
    float4 lo = make_float4(a[0], a[1], a[2], a[3]);
    float4 hi = make_float4(a[4], a[5], a[6], __int_as_float(src[i]));
    float4* o = (float4*)(sea + (size_t)pos * 8);
    o[0] = lo;
    o[1] = hi;
  }
}

// Aggregation: static map, wave serves NPW consecutive nodes. Flat edge
// loop over the wave's whole CSR range in 8-wide groups, in-order issue and
// immediate consume (empirically optimal; deeper pipelines regress FETCH).
// MODE 0: layer 0, single-row node table. MODE 1: layer 0, general table.
// MODE 2: later layers, h = relu(affine(prev z)) gathered per edge.
#define NPW 8
template<int MODE>
__global__ __launch_bounds__(256)
void agg_k(const float* __restrict__ hprev, const int* __restrict__ x,
           const float* __restrict__ ntab, const int* __restrict__ rowptr,
           const float* __restrict__ sea, const float* __restrict__ ewl,
           const float* __restrict__ ebl, const float* __restrict__ statsP,
           const float* __restrict__ gamP, const float* __restrict__ betP,
           float* __restrict__ zout, int n) {
  int wv = (blockIdx.x * blockDim.x + threadIdx.x) >> 6;
  int lane = threadIdx.x & 63;
  int g0 = wv * NPW;
  if (g0 >= n) return;
  int gend = g0 + NPW; if (gend > n) gend = n;

  float ew_[7];
#pragma unroll
  for (int k = 0; k < 7; k++) ew_[k] = ewl[k * 64 + lane];
  float ebv = ebl[lane];

  float cnst = 0.f, sc = 1.f, sh = 0.f;
  if (MODE == 0) cnst = ntab[lane];
  if (MODE == 2) {
    float s1 = statsP[lane], s2 = statsP[64 + lane];
    float mu = s1 / (float)n;
    float var = s2 / (float)n - mu * mu;
    sc = gamP[lane] * rsqrtf(var + 1e-5f);
    sh = betP[lane] - mu * sc;
  }

  // raw self/gather load (affine+relu applied at use for MODE 2)
  auto raw_ld = [&](int row) -> float {
    if (MODE == 0) return 0.f;
    if (MODE == 1) {
      int xv = __builtin_amdgcn_readfirstlane(x[row]);
      return ntab[(size_t)xv * 64 + lane];
    }
    return hprev[(size_t)row * 64 + lane];
  };
  auto finish_h = [&](float v) -> float {
    if (MODE == 0) return cnst;
    if (MODE == 1) return v;
    return fmaxf(fmaf(v, sc, sh), 0.f);
  };

  int P1 = __builtin_amdgcn_readfirstlane(rowptr[gend]);
  int p0 = __builtin_amdgcn_readfirstlane(rowptr[g0]);
  int nd = g0;
  int pn = __builtin_amdgcn_readfirstlane(rowptr[nd + 1]);
  float selfv = raw_ld(nd);
  float acc = 0.f;

  for (int p = p0; p < P1; p += 8) {
    // scalar attr rows + src ids for 8 edges (clamped); SGPR-resident
    const float* R[8];
    int s[8];
#pragma unroll
    for (int u = 0; u < 8; u++) {
      int t = p + u;
      int q = t < P1 ? t : P1 - 1;
      R[u] = sea + (size_t)q * 8;
      s[u] = __builtin_amdgcn_readfirstlane(__float_as_int(R[u][7]));
    }
    // 8 independent per-lane gathers in flight
    float h[8];
#pragma unroll
    for (int u = 0; u < 8; u++) h[u] = (MODE == 0) ? cnst : raw_ld(s[u]);
    // edge embeddings (overlaps gather latency; SGPR x VGPR fma)
    float m[8];
#pragma unroll
    for (int u = 0; u < 8; u++) m[u] = ebv;
#pragma unroll
    for (int k = 0; k < 7; k++) {
#pragma unroll
      for (int u = 0; u < 8; u++) m[u] = fmaf(R[u][k], ew_[k], m[u]);
    }
    // consume with node-boundary flush
#pragma unroll
    for (int u = 0; u < 8; u++) {
      if (p + u < P1) {
        while (p + u >= pn) {
          zout[(size_t)nd * 64 + lane] = finish_h(selfv) + acc;
          nd++;
          selfv = raw_ld(nd);
          pn = __builtin_amdgcn_readfirstlane(rowptr[nd + 1]);
          acc = 0.f;
        }
        acc += fmaxf(finish_h(h[u]) + m[u], 0.f);
      }
    }
  }
  // drain: flush current node and trailing zero-edge nodes
  while (nd < gend) {
    zout[(size_t)nd * 64 + lane] = finish_h(selfv) + acc;
    nd++;
    acc = 0.f;
    if (nd < gend) selfv = raw_ld(nd);
  }
}

// MLP: z2 = relu(z @ w1 + b1) @ w2 + b2, per-dim sum/sumsq into this
// layer's stat slot. Tiled GEMM: 256 threads (16x16), 128 rows x 64 cols,
// 8x4 register tile. A transposed in LDS with stride 132 (b128 feeds);
// w1/w2 staged through Ws.
#define ASTR 132
__global__ __launch_bounds__(256, 3)
void mlp_k(const float* __restrict__ zin, const float* __restrict__ w1l,
           const float* __restrict__ b1l, const float* __restrict__ w2l,
           const float* __restrict__ b2l, float* __restrict__ zout,
           float* __restrict__ statslot, int n) {
  __shared__ float As[64 * ASTR];
  __shared__ float Ws[4096];
  __shared__ float red[128];
  int tid = threadIdx.x;
  int tx = tid & 15, ty = tid >> 4;
  if (tid < 128) red[tid] = 0.f;
  int r0 = blockIdx.x * 128;

  // stage A transposed + w1
  {
    const float4* gz = (const float4*)(zin + (size_t)r0 * 64);
#pragma unroll
    for (int it = 0; it < 8; it++) {
      int f4 = it * 256 + tid;                 // 128 rows x 16 quads
      int row = f4 >> 4, kq = f4 & 15;
      float4 v = make_float4(0.f, 0.f, 0.f, 0.f);
      if (r0 + row < n) v = gz[f4];
      As[(4 * kq + 0) * ASTR + row] = v.x;
      As[(4 * kq + 1) * ASTR + row] = v.y;
      As[(4 * kq + 2) * ASTR + row] = v.z;
      As[(4 * kq + 3) * ASTR + row] = v.w;
    }
    const float4* wa = (const float4*)w1l;
    float4* wd = (float4*)Ws;
#pragma unroll
    for (int it = 0; it < 4; it++) wd[it * 256 + tid] = wa[it * 256 + tid];
  }
  __syncthreads();

  const float4 b1v = *(const float4*)(b1l + tx * 4);
  float t[8][4];
#pragma unroll
  for (int rr = 0; rr < 8; rr++) {
    t[rr][0] = b1v.x; t[rr][1] = b1v.y; t[rr][2] = b1v.z; t[rr][3] = b1v.w;
  }
#pragma unroll 8
  for (int k = 0; k < 64; k++) {
    float4 aA = *(const float4*)&As[k * ASTR + ty * 8];
    float4 aB = *(const float4*)&As[k * ASTR + ty * 8 + 4];
    float4 b = *(const float4*)&Ws[k * 64 + tx * 4];
    float a[8] = {aA.x, aA.y, aA.z, aA.w, aB.x, aB.y, aB.z, aB.w};
#pragma unroll
    for (int rr = 0; rr < 8; rr++) {
      t[rr][0] = fmaf(a[rr], b.x, t[rr][0]);
      t[rr][1] = fmaf(a[rr], b.y, t[rr][1]);
      t[rr][2] = fmaf(a[rr], b.z, t[rr][2]);
      t[rr][3] = fmaf(a[rr], b.w, t[rr][3]);
    }
  }
  __syncthreads();                             // As, Ws fully consumed

  // relu(t) transposed into As; stage w2
#pragma unroll
  for (int cc = 0; cc < 4; cc++)
#pragma unroll
    for (int rr = 0; rr < 8; rr++)
      As[(tx * 4 + cc) * ASTR + ty * 8 + rr] = fmaxf(t[rr][cc], 0.f);
  {
    const float4* wb = (const float4*)w2l;
    float4* wd = (float4*)Ws;
#pragma unroll
    for (int it = 0; it < 4; it++) wd[it * 256 + tid] = wb[it * 256 + tid];
  }
  __syncthreads();

  const float4 b2v = *(const float4*)(b2l + tx * 4);
  float o[8][4];
#pragma unroll
  for (int rr = 0; rr < 8; rr++) {
    o[rr][0] = b2v.x; o[rr][1] = b2v.y; o[rr][2] = b2v.z; o[rr][3] = b2v.w;
  }
#pragma unroll 8
  for (int k = 0; k < 64; k++) {
    float4 aA = *(const float4*)&As[k * ASTR + ty * 8];
    float4 aB = *(const float4*)&As[k * ASTR + ty * 8 + 4];
    float4 b = *(const float4*)&Ws[k * 64 + tx * 4];
    float a[8] = {aA.x, aA.y, aA.z, aA.w, aB.x, aB.y, aB.z, aB.w};
#pragma unroll
    for (int rr = 0; rr < 8; rr++) {
      o[rr][0] = fmaf(a[rr], b.x, o[rr][0]);
      o[rr][1] = fmaf(a[rr], b.y, o[rr][1]);
      o[rr][2] = fmaf(a[rr], b.z, o[rr][2]);
      o[rr][3] = fmaf(a[rr], b.w, o[rr][3]);
    }
  }

  // store + BN stat partials (valid rows only)
  float s1[4] = {0.f, 0.f, 0.f, 0.f}, s2[4] = {0.f, 0.f, 0.f, 0.f};
#pragma unroll
  for (int rr = 0; rr < 8; rr++) {
    int grow = r0 + ty * 8 + rr;
    if (grow < n) {
      float4 v = make_float4(o[rr][0], o[rr][1], o[rr][2], o[rr][3]);
      *(float4*)(zout + (size_t)grow * 64 + tx * 4) = v;
#pragma unroll
      for (int cc = 0; cc < 4; cc++) {
        s1[cc] += o[rr][cc];
        s2[cc] = fmaf(o[rr][cc], o[rr][cc], s2[cc]);
      }
    }
  }
#pragma unroll
  for (int cc = 0; cc < 4; cc++) {             // reduce over the 4 ty-groups in wave
    s1[cc] += __shfl_xor(s1[cc], 16); s1[cc] += __shfl_xor(s1[cc], 32);
    s2[cc] += __shfl_xor(s2[cc], 16); s2[cc] += __shfl_xor(s2[cc], 32);
  }
  if ((tid & 48) == 0) {                       // one ty-group per wave
#pragma unroll
    for (int cc = 0; cc < 4; cc++) {
      atomicAdd(&red[tx * 4 + cc], s1[cc]);
      atomicAdd(&red[64 + tx * 4 + cc], s2[cc]);
    }
  }
  __syncthreads();
  if (tid < 128) atomicAdd(&statslot[tid], red[tid]);
}

// Segment-mean pool with last-layer BN affine fused (no relu on last layer).
__global__ void pool_k(const float* __restrict__ z2, const float* __restrict__ stats,
                       const float* __restrict__ gam, const float* __restrict__ bet,
                       const int* __restrict__ batch, float* __restrict__ gsum,
                       float* __restrict__ gcnt, int n, int ch) {
  int wid = (blockIdx.x * blockDim.x + threadIdx.x) >> 6;
  int lane = threadIdx.x & 63;
  int v0 = wid * ch;
  if (v0 >= n) return;
  int v1 = v0 + ch; if (v1 > n) v1 = n;
  float st1 = stats[lane], st2 = stats[64 + lane];
  float mu = st1 / (float)n;
  float var = st2 / (float)n - mu * mu;
  float sc = gam[lane] * rsqrtf(var + 1e-5f);
  float sh = bet[lane] - mu * sc;
  int curb = batch[v0];
  float acc = 0.f;
  int cnt = 0;
  for (int v = v0; v < v1; v++) {
    int b = batch[v];
    if (b != curb) {
      atomicAdd(&gsum[curb * 64 + lane], acc);
      if (lane == 0) atomicAdd(&gcnt[curb], (float)cnt);
      acc = 0.f; cnt = 0; curb = b;
    }
    acc += fmaf(z2[(size_t)v * 64 + lane], sc, sh);
    cnt++;
  }
  atomicAdd(&gsum[curb * 64 + lane], acc);
  if (lane == 0) atomicAdd(&gcnt[curb], (float)cnt);
}

__global__ void head_k(const float* __restrict__ gsum, const float* __restrict__ gcnt,
                       const float* __restrict__ pw, const float* __restrict__ pb,
                       float* __restrict__ out, int B, int C) {
  for (int idx = threadIdx.x; idx < B * C; idx += blockDim.x) {
    int g = idx / C, c = idx % C;
    float inv = 1.f / fmaxf(gcnt[g], 1.f);
    float s = pb[c];
    for (int d = 0; d < 64; d++)
      s = fmaf(gsum[g * 64 + d] * inv, pw[d * C + c], s);
    out[idx] = s;
  }
}

extern "C" void kernel_launch(void* const* d_in, const int* in_sizes, int n_in,
                              void* d_out, int out_size, void* d_ws, size_t ws_size,
                              hipStream_t stream) {
  const int*   x     = (const int*)d_in[0];
  const int*   ei    = (const int*)d_in[1];
  const float* ea    = (const float*)d_in[2];
  const int*   batch = (const int*)d_in[3];
  const float* ntab  = (const float*)d_in[4];
  const float* ew    = (const float*)d_in[5];
  const float* eb    = (const float*)d_in[6];
  const float* w1    = (const float*)d_in[7];
  const float* b1    = (const float*)d_in[8];
  const float* w2    = (const float*)d_in[9];
  const float* b2    = (const float*)d_in[10];
  const float* gamma = (const float*)d_in[11];
  const float* beta  = (const float*)d_in[12];
  const float* pw    = (const float*)d_in[13];
  const float* pb    = (const float*)d_in[14];
  float* out = (float*)d_out;

  int N = in_sizes[0];
  int E = in_sizes[1] / 2;
  int L = in_sizes[6] / 64;        // eb is (L, 64)
  int C = in_sizes[14];
  int B = out_size / C;
  bool tab1 = (in_sizes[4] == 64); // node_table has a single row

  const int* src = ei;
  const int* dst = ei + E;

  // workspace carve (256B aligned)
  char* ws = (char*)d_ws;
  auto alloc = [&](size_t bytes) -> char* {
    char* p = ws;
    ws += (bytes + 255) & ~(size_t)255;
    return p;
  };
  float* hbuf    = (float*)alloc((size_t)N * 64 * 4);  // layer output (MLP out)
  float* tbuf    = (float*)alloc((size_t)N * 64 * 4);  // agg intermediate
  int*   rowptr  = (int*)alloc((size_t)(N + 1) * 4);
  int*   cur     = (int*)alloc((size_t)N * 4);
  float* sea     = (float*)alloc((size_t)(E + 16) * 8 * 4); // CSR rows + pad
  int*   bsum    = (int*)alloc(512 * 4);
  float* bnstats = (float*)alloc((size_t)L * 128 * 4);     // per-layer stat slots
  float* gsum    = (float*)alloc((size_t)B * 64 * 4);
  float* gcnt    = (float*)alloc((size_t)B * 4);

  hipMemsetAsync(cur, 0, (size_t)N * 4, stream);
  hipMemsetAsync(bnstats, 0, (size_t)L * 128 * 4, stream);
  hipMemsetAsync(gsum, 0, (size_t)B * 64 * 4, stream);
  hipMemsetAsync(gcnt, 0, (size_t)B * 4, stream);

  // CSR build (reused across all layers)
  hist_k<<<2048, 256, 0, stream>>>(dst, cur, E);
  int NB = (N + 255) / 256;
  scan_a_k<<<NB, 256, 0, stream>>>(cur, rowptr, bsum, N);
  scan_b_k<<<1, 512, 0, stream>>>(bsum, NB);
  scan_c_k<<<NB, 256, 0, stream>>>(rowptr, cur, bsum, N, E);
  scatter_k<<<4096, 256, 0, stream>>>(src, dst, cur, sea, ea, E);

  int aggWaves = (N + NPW - 1) / NPW;
  int aggBlocks = (aggWaves * 64 + 255) / 256;
  int mlpBlocks = (N + 127) / 128;
  for (int l = 0; l < L; l++) {
    const float* ewl = ew + (size_t)l * 448;
    const float* ebl = eb + (size_t)l * 64;
    const float* stP = bnstats + (size_t)(l > 0 ? l - 1 : 0) * 128;
    const float* gmP = gamma + (size_t)(l > 0 ? l - 1 : 0) * 64;
    const float* btP = beta + (size_t)(l > 0 ? l - 1 : 0) * 64;
    // agg: reads hbuf (layers>0), writes tbuf
    if (l == 0) {
      if (tab1)
        agg_k<0><<<aggBlocks, 256, 0, stream>>>(hbuf, x, ntab, rowptr, sea, ewl,
                                                ebl, stP, gmP, btP, tbuf, N);
      else
        agg_k<1><<<aggBlocks, 256, 0, stream>>>(hbuf, x, ntab, rowptr, sea, ewl,
                                                ebl, stP, gmP, btP, tbuf, N);
    } else {
      agg_k<2><<<aggBlocks, 256, 0, stream>>>(hbuf, x, ntab, rowptr, sea, ewl,
                                              ebl, stP, gmP, btP, tbuf, N);
    }
    // MLP: reads tbuf, writes hbuf (the next layer's h / pool input)
    mlp_k<<<mlpBlocks, 256, 0, stream>>>(tbuf, w1 + (size_t)l * 4096,
                                         b1 + (size_t)l * 64,
                                         w2 + (size_t)l * 4096,
                                         b2 + (size_t)l * 64,
                                         hbuf, bnstats + (size_t)l * 128, N);
  }

  int ch = 64;
  int poolWaves = (N + ch - 1) / ch;
  int poolBlocks = (poolWaves + 3) / 4;
  pool_k<<<poolBlocks, 256, 0, stream>>>(hbuf,
                                         bnstats + (size_t)(L - 1) * 128,
                                         gamma + (size_t)(L - 1) * 64,
                                         beta + (size_t)(L - 1) * 64,
                                         batch, gsum, gcnt, N, ch);
  head_k<<<1, 256, 0, stream>>>(gsum, gcnt, pw, pb, out, B, C);
}